// Round 5
// baseline (103.527 us; speedup 1.0000x reference)
//
#include <hip/hip_runtime.h>
#include <hip/hip_cooperative_groups.h>
#include <math.h>

namespace cg = cooperative_groups;

#define B_  16
#define C_  2048
#define P_  16
#define CR_ 128

// ===================== Fused cooperative kernel =====================
// grid = 256 blocks x 512 threads, 1 block/CU (64 KiB LDS, launch_bounds(512,2)).
// P1: patch means -> y (global).  grid.sync.
// P2: fc1+relu, y staged to LDS in two 64KiB halves -> h (global).  grid.sync.
// P3: fc2+sigmoid, h[p] staged to LDS -> out.
__global__ void __launch_bounds__(512, 2) k_fused(
    const float* __restrict__ x, const float* __restrict__ w1,
    const float* __restrict__ w2, float* __restrict__ out,
    float* __restrict__ y, float* __restrict__ h)
{
    __shared__ float smem[16 * 1024];                 // 64 KiB
    float4* sm4 = reinterpret_cast<float4*>(smem);
    const int tid  = threadIdx.x;
    const int wib  = tid >> 6;
    const int lane = tid & 63;
    const int bid  = blockIdx.x;

    // ---------- Phase 1: y[b][c] = mean of x[b,c,16:32,16:32] ----------
    {
        const int wid = bid * 8 + wib;                // [0,2048), 16 patches/wave
        const int row = lane >> 2, col = (lane & 3) * 4;
        const float* base = x + (size_t)wid * 16 * 4096 + (16 * 64 + 16)
                          + row * 64 + col;
        #pragma unroll
        for (int g = 0; g < 2; ++g) {
            float s[8];
            #pragma unroll
            for (int j = 0; j < 8; ++j) {
                float4 v = *reinterpret_cast<const float4*>(base + (g * 8 + j) * 4096);
                s[j] = (v.x + v.y) + (v.z + v.w);
            }
            #pragma unroll
            for (int j = 0; j < 8; ++j) {
                #pragma unroll
                for (int m = 32; m >= 1; m >>= 1) s[j] += __shfl_xor(s[j], m, 64);
            }
            float v = s[0];
            v = (lane == 1) ? s[1] : v;
            v = (lane == 2) ? s[2] : v;
            v = (lane == 3) ? s[3] : v;
            v = (lane == 4) ? s[4] : v;
            v = (lane == 5) ? s[5] : v;
            v = (lane == 6) ? s[6] : v;
            v = (lane == 7) ? s[7] : v;
            if (lane < 8) y[wid * 16 + g * 8 + lane] = v * (1.0f / 256.0f);
        }
    }

    cg::this_grid().sync();

    // ---------- Phase 2: h[p][b][k] = relu(W1[p][k][:] . y[b][:]) ----------
    {
        const float4* yv  = reinterpret_cast<const float4*>(y);
        const float4* w1v = reinterpret_cast<const float4*>(w1);
        const bool work = (wib < 4);                  // 4 working waves/block
        const int r0 = (bid * 4 + wib) * 2;           // rows r0, r0+1 (same p)

        float4 wA[8], wB[8];                          // full W1 rows up-front
        if (work) {
            #pragma unroll
            for (int i = 0; i < 8; ++i) {
                wA[i] = w1v[(size_t)r0 * 512 + i * 64 + lane];
                wB[i] = w1v[(size_t)(r0 + 1) * 512 + i * 64 + lane];
            }
        }
        float acc0[16], acc1[16];
        #pragma unroll
        for (int b = 0; b < 16; ++b) { acc0[b] = 0.f; acc1[b] = 0.f; }

        #pragma unroll
        for (int pass = 0; pass < 2; ++pass) {
            // stage y[:, pass*1024 : +1024] as [16][256] float4
            #pragma unroll
            for (int i = 0; i < 8; ++i) {
                int f = i * 512 + tid;                // [0,4096)
                int b = f >> 8, c4 = f & 255;
                sm4[f] = yv[b * 512 + pass * 256 + c4];
            }
            __syncthreads();
            if (work) {
                #pragma unroll
                for (int il = 0; il < 4; ++il) {
                    float4 wa = wA[pass * 4 + il];    // static after unroll
                    float4 wb = wB[pass * 4 + il];
                    #pragma unroll
                    for (int b = 0; b < 16; ++b) {
                        float4 v = sm4[b * 256 + il * 64 + lane];
                        acc0[b] += wa.x * v.x + wa.y * v.y + wa.z * v.z + wa.w * v.w;
                        acc1[b] += wb.x * v.x + wb.y * v.y + wb.z * v.z + wb.w * v.w;
                    }
                }
            }
            __syncthreads();
        }

        if (work) {
            #pragma unroll
            for (int b = 0; b < 16; ++b) {
                #pragma unroll
                for (int m = 32; m >= 1; m >>= 1) {
                    acc0[b] += __shfl_xor(acc0[b], m, 64);
                    acc1[b] += __shfl_xor(acc1[b], m, 64);
                }
            }
            float v0 = acc0[0], v1 = acc1[0];
            #pragma unroll
            for (int b = 1; b < 16; ++b) {
                v0 = (lane == b) ? acc0[b] : v0;
                v1 = (lane == b) ? acc1[b] : v1;
            }
            if (lane < 16) {
                const int p = r0 >> 7, k = r0 & 127;
                h[(p * B_ + lane) * CR_ + k]     = fmaxf(v0, 0.f);
                h[(p * B_ + lane) * CR_ + k + 1] = fmaxf(v1, 0.f);
            }
        }
    }

    cg::this_grid().sync();

    // ---------- Phase 3: out[p][b][c] = sigmoid(W2[p][c][:] . h[p][b][:]) ----------
    {
        const int p   = bid >> 4;
        const int c0  = (bid & 15) * 128 + wib * 16;  // 16 c-rows per wave
        const int row = lane >> 2, q = lane & 3;

        const float4* hv = reinterpret_cast<const float4*>(h);
        sm4[tid] = hv[p * 512 + tid];                 // stage h[p] (8 KiB)
        __syncthreads();

        const float4* wr = reinterpret_cast<const float4*>(w2)
                         + ((size_t)p * C_ + c0 + row) * (CR_ / 4);
        float4 wv[8];
        #pragma unroll
        for (int j = 0; j < 8; ++j) wv[j] = wr[q + 4 * j];

        float acc[16];
        #pragma unroll
        for (int b = 0; b < 16; ++b) acc[b] = 0.f;
        #pragma unroll
        for (int j = 0; j < 8; ++j) {
            #pragma unroll
            for (int b = 0; b < 16; ++b) {
                float4 h4 = sm4[b * 32 + q + 4 * j];  // 4 distinct + broadcast
                acc[b] += wv[j].x * h4.x + wv[j].y * h4.y
                        + wv[j].z * h4.z + wv[j].w * h4.w;
            }
        }
        #pragma unroll
        for (int b = 0; b < 16; ++b) {
            acc[b] += __shfl_xor(acc[b], 1, 64);
            acc[b] += __shfl_xor(acc[b], 2, 64);
        }
        #pragma unroll
        for (int i = 0; i < 4; ++i) {
            float v = acc[i];
            v = (q == 1) ? acc[4 + i]  : v;
            v = (q == 2) ? acc[8 + i]  : v;
            v = (q == 3) ? acc[12 + i] : v;
            int b = q * 4 + i;
            out[(((size_t)p * B_ + b) << 11) + c0 + row] = 1.0f / (1.0f + expf(-v));
        }
    }
}

// ===================== Fallback: R4 3-kernel path =====================
__global__ void k_mean(const float* __restrict__ x, float* __restrict__ y) {
    int wave = blockIdx.x * (blockDim.x >> 6) + (threadIdx.x >> 6);
    int lane = threadIdx.x & 63;
    int row = lane >> 2, col = (lane & 3) * 4;
    const float* base = x + (size_t)wave * 4 * 4096 + (16 * 64 + 16) + row * 64 + col;
    float4 v0 = *reinterpret_cast<const float4*>(base);
    float4 v1 = *reinterpret_cast<const float4*>(base + 4096);
    float4 v2 = *reinterpret_cast<const float4*>(base + 8192);
    float4 v3 = *reinterpret_cast<const float4*>(base + 12288);
    float s0 = v0.x + v0.y + v0.z + v0.w;
    float s1 = v1.x + v1.y + v1.z + v1.w;
    float s2 = v2.x + v2.y + v2.z + v2.w;
    float s3 = v3.x + v3.y + v3.z + v3.w;
    #pragma unroll
    for (int m = 32; m >= 1; m >>= 1) {
        s0 += __shfl_xor(s0, m, 64); s1 += __shfl_xor(s1, m, 64);
        s2 += __shfl_xor(s2, m, 64); s3 += __shfl_xor(s3, m, 64);
    }
    float v = s0;
    v = (lane == 1) ? s1 : v; v = (lane == 2) ? s2 : v; v = (lane == 3) ? s3 : v;
    if (lane < 4) y[wave * 4 + lane] = v * (1.0f / 256.0f);
}

__global__ void __launch_bounds__(256) k_fc1(const float* __restrict__ w1,
                                             const float* __restrict__ y,
                                             float* __restrict__ h) {
    __shared__ float ys[B_ * C_ / 2];                 // 64 KiB half
    int tid = threadIdx.x, wib = tid >> 6, lane = tid & 63;
    const float4* yv = reinterpret_cast<const float4*>(y);
    float4* sm4 = reinterpret_cast<float4*>(ys);
    int r0 = blockIdx.x * 8 + wib * 2;
    const float4* wr0 = reinterpret_cast<const float4*>(w1) + (size_t)r0 * 512;
    const float4* wr1 = wr0 + 512;
    float4 wA[8], wB[8];
    #pragma unroll
    for (int i = 0; i < 8; ++i) { wA[i] = wr0[i * 64 + lane]; wB[i] = wr1[i * 64 + lane]; }
    float acc0[16], acc1[16];
    #pragma unroll
    for (int b = 0; b < 16; ++b) { acc0[b] = 0.f; acc1[b] = 0.f; }
    #pragma unroll
    for (int pass = 0; pass < 2; ++pass) {
        #pragma unroll
        for (int i = 0; i < 16; ++i) {
            int f = i * 256 + tid;
            int b = f >> 8, c4 = f & 255;
            sm4[f] = yv[b * 512 + pass * 256 + c4];
        }
        __syncthreads();
        #pragma unroll
        for (int il = 0; il < 4; ++il) {
            float4 wa = wA[pass * 4 + il], wb = wB[pass * 4 + il];
            #pragma unroll
            for (int b = 0; b < 16; ++b) {
                float4 v = sm4[b * 256 + il * 64 + lane];
                acc0[b] += wa.x * v.x + wa.y * v.y + wa.z * v.z + wa.w * v.w;
                acc1[b] += wb.x * v.x + wb.y * v.y + wb.z * v.z + wb.w * v.w;
            }
        }
        __syncthreads();
    }
    #pragma unroll
    for (int b = 0; b < 16; ++b) {
        #pragma unroll
        for (int m = 32; m >= 1; m >>= 1) {
            acc0[b] += __shfl_xor(acc0[b], m, 64);
            acc1[b] += __shfl_xor(acc1[b], m, 64);
        }
    }
    float v0 = acc0[0], v1 = acc1[0];
    #pragma unroll
    for (int b = 1; b < 16; ++b) {
        v0 = (lane == b) ? acc0[b] : v0;
        v1 = (lane == b) ? acc1[b] : v1;
    }
    if (lane < 16) {
        int p = r0 >> 7, k = r0 & 127;
        h[(p * B_ + lane) * CR_ + k]     = fmaxf(v0, 0.f);
        h[(p * B_ + lane) * CR_ + k + 1] = fmaxf(v1, 0.f);
    }
}

__global__ void __launch_bounds__(256) k_fc2(const float* __restrict__ w2,
                                             const float* __restrict__ h,
                                             float* __restrict__ out) {
    __shared__ float hs[B_ * CR_];
    int wib = threadIdx.x >> 6;
    int wid = blockIdx.x * 4 + wib;
    int lane = threadIdx.x & 63;
    int p = wid >> 7, c0 = (wid & 127) << 4;
    int row = lane >> 2, q = lane & 3;
    const float4* hsrc = reinterpret_cast<const float4*>(h + (size_t)p * B_ * CR_);
    float4* hdst = reinterpret_cast<float4*>(hs);
    #pragma unroll
    for (int i = 0; i < 2; ++i) hdst[threadIdx.x + i * 256] = hsrc[threadIdx.x + i * 256];
    __syncthreads();
    const float4* wr = reinterpret_cast<const float4*>(w2)
                     + ((size_t)p * C_ + c0 + row) * (CR_ / 4);
    const float4* hv = reinterpret_cast<const float4*>(hs);
    float acc[16];
    #pragma unroll
    for (int b = 0; b < 16; ++b) acc[b] = 0.f;
    #pragma unroll
    for (int j = 0; j < 8; ++j) {
        float4 w4 = wr[q + 4 * j];
        #pragma unroll
        for (int b = 0; b < 16; ++b) {
            float4 h4 = hv[b * 32 + q + 4 * j];
            acc[b] += w4.x * h4.x + w4.y * h4.y + w4.z * h4.z + w4.w * h4.w;
        }
    }
    #pragma unroll
    for (int b = 0; b < 16; ++b) {
        acc[b] += __shfl_xor(acc[b], 1, 64);
        acc[b] += __shfl_xor(acc[b], 2, 64);
    }
    #pragma unroll
    for (int i = 0; i < 4; ++i) {
        float v = acc[i];
        v = (q == 1) ? acc[4 + i] : v;
        v = (q == 2) ? acc[8 + i] : v;
        v = (q == 3) ? acc[12 + i] : v;
        int b = q * 4 + i;
        out[(((size_t)p * B_ + b) << 11) + c0 + row] = 1.0f / (1.0f + expf(-v));
    }
}

extern "C" void kernel_launch(void* const* d_in, const int* in_sizes, int n_in,
                              void* d_out, int out_size, void* d_ws, size_t ws_size,
                              hipStream_t stream) {
    const float* x  = (const float*)d_in[0];
    const float* w1 = (const float*)d_in[1];
    const float* w2 = (const float*)d_in[2];
    float* out = (float*)d_out;
    float* y = (float*)d_ws;                 // 32768 floats
    float* h = y + B_ * C_;                  // 32768 floats

    void* args[] = { (void*)&x, (void*)&w1, (void*)&w2, (void*)&out,
                     (void*)&y, (void*)&h };
    hipError_t err = hipLaunchCooperativeKernel((const void*)k_fused,
                                                dim3(256), dim3(512),
                                                args, 0, stream);
    if (err != hipSuccess) {
        // Fallback: 3-kernel path (deterministic; same result).
        k_mean<<<(B_ * C_ / 4) / 4, 256, 0, stream>>>(x, y);
        k_fc1<<<256, 256, 0, stream>>>(w1, y, h);
        k_fc2<<<(P_ * C_ / 16) / 4, 256, 0, stream>>>(w2, h, out);
    }
}

// Round 6
// 88.071 us; speedup vs baseline: 1.1755x; 1.1755x over previous
//
#include <hip/hip_runtime.h>
#include <math.h>

#define B_  16
#define C_  2048
#define P_  16
#define CR_ 128

// ---------------------------------------------------------------------------
// Lightweight grid barrier: counters in d_ws, zeroed by hipMemsetAsync before
// each launch. Cooperative launch guarantees all 256 blocks co-resident.
// __syncthreads() drains vmcnt -> block's global stores are in L2; leader's
// ACQ_REL agent-scope atomic + acquire spin provide cross-XCD visibility.
// ---------------------------------------------------------------------------
__device__ __forceinline__ void gbar(unsigned* ctr, unsigned nblk) {
    __syncthreads();
    if (threadIdx.x == 0) {
        __hip_atomic_fetch_add(ctr, 1u, __ATOMIC_ACQ_REL, __HIP_MEMORY_SCOPE_AGENT);
        while (__hip_atomic_load(ctr, __ATOMIC_ACQUIRE, __HIP_MEMORY_SCOPE_AGENT) < nblk)
            __builtin_amdgcn_s_sleep(1);
    }
    __syncthreads();
}

// ===================== Fused kernel, custom barriers =====================
// grid = 256 blocks x 512 threads, 1 block/CU. 64 KiB LDS.
// P1: patch means -> y.  gbar.  P2: fc1+relu -> h2[p][slice][b][k'] (each
// block writes a line-exclusive 512B region).  gbar.  P3: fc2+sigmoid -> out.
__global__ void __launch_bounds__(512, 2) k_fused(
    const float* __restrict__ x, const float* __restrict__ w1,
    const float* __restrict__ w2, float* __restrict__ out,
    float* __restrict__ y, float* __restrict__ h2, unsigned* __restrict__ bars)
{
    __shared__ float smem[16 * 1024];                 // 64 KiB
    float4* sm4 = reinterpret_cast<float4*>(smem);
    const int tid  = threadIdx.x;
    const int wib  = tid >> 6;
    const int lane = tid & 63;
    const int bid  = blockIdx.x;

    // ---------- Phase 1: y[b][c] = mean of x[b,c,16:32,16:32] ----------
    {
        const int wid = bid * 8 + wib;                // [0,2048), 16 patches/wave
        const int row = lane >> 2, col = (lane & 3) * 4;
        const float* base = x + (size_t)wid * 16 * 4096 + (16 * 64 + 16)
                          + row * 64 + col;
        #pragma unroll
        for (int g = 0; g < 2; ++g) {
            float s[8];
            #pragma unroll
            for (int j = 0; j < 8; ++j) {
                float4 v = *reinterpret_cast<const float4*>(base + (g * 8 + j) * 4096);
                s[j] = (v.x + v.y) + (v.z + v.w);
            }
            #pragma unroll
            for (int j = 0; j < 8; ++j) {
                #pragma unroll
                for (int m = 32; m >= 1; m >>= 1) s[j] += __shfl_xor(s[j], m, 64);
            }
            float v = s[0];
            v = (lane == 1) ? s[1] : v;
            v = (lane == 2) ? s[2] : v;
            v = (lane == 3) ? s[3] : v;
            v = (lane == 4) ? s[4] : v;
            v = (lane == 5) ? s[5] : v;
            v = (lane == 6) ? s[6] : v;
            v = (lane == 7) ? s[7] : v;
            if (lane < 8) y[wid * 16 + g * 8 + lane] = v * (1.0f / 256.0f);
        }
    }

    gbar(&bars[0], 256u);

    // ---------- Phase 2: h2 = relu(W1 . y), block-exclusive h2 region ----------
    {
        const float4* yv  = reinterpret_cast<const float4*>(y);
        const float4* w1v = reinterpret_cast<const float4*>(w1);
        const bool work = (wib < 4);                  // 4 working waves/block
        const int r0 = (bid * 4 + wib) * 2;           // rows r0, r0+1 (same p)
        const float4* wr0 = w1v + (size_t)r0 * 512;
        const float4* wr1 = wr0 + 512;

        float acc0[16], acc1[16];
        #pragma unroll
        for (int b = 0; b < 16; ++b) { acc0[b] = 0.f; acc1[b] = 0.f; }

        float4 pa, pb;
        if (work) { pa = wr0[lane]; pb = wr1[lane]; }
        int chunk = 0;

        #pragma unroll
        for (int pass = 0; pass < 2; ++pass) {
            // stage y[:, pass*1024 : +1024] as [16][256] float4
            #pragma unroll
            for (int i = 0; i < 8; ++i) {
                int f = i * 512 + tid;                // [0,4096)
                int b = f >> 8, c4 = f & 255;
                sm4[f] = yv[b * 512 + pass * 256 + c4];
            }
            __syncthreads();
            if (work) {
                #pragma unroll
                for (int il = 0; il < 4; ++il) {
                    float4 wa = pa, wb = pb;
                    if (chunk < 7) {                  // prefetch one chunk ahead
                        pa = wr0[(chunk + 1) * 64 + lane];
                        pb = wr1[(chunk + 1) * 64 + lane];
                    }
                    #pragma unroll
                    for (int b = 0; b < 16; ++b) {
                        float4 v = sm4[b * 256 + il * 64 + lane];
                        acc0[b] += wa.x * v.x + wa.y * v.y + wa.z * v.z + wa.w * v.w;
                        acc1[b] += wb.x * v.x + wb.y * v.y + wb.z * v.z + wb.w * v.w;
                    }
                    ++chunk;
                }
            }
            __syncthreads();
        }

        if (work) {
            #pragma unroll
            for (int b = 0; b < 16; ++b) {
                #pragma unroll
                for (int m = 32; m >= 1; m >>= 1) {
                    acc0[b] += __shfl_xor(acc0[b], m, 64);
                    acc1[b] += __shfl_xor(acc1[b], m, 64);
                }
            }
            float v0 = acc0[0], v1 = acc1[0];
            #pragma unroll
            for (int b = 1; b < 16; ++b) {
                v0 = (lane == b) ? acc0[b] : v0;
                v1 = (lane == b) ? acc1[b] : v1;
            }
            if (lane < 16) {
                // h2[p][m][b][k']: p=r0>>7, m=bid&15, b=lane, k'=2*wib (+1)
                const int p = r0 >> 7;
                const int idx = p * 2048 + (bid & 15) * 128 + lane * 8 + 2 * wib;
                h2[idx]     = fmaxf(v0, 0.f);
                h2[idx + 1] = fmaxf(v1, 0.f);
            }
        }
    }

    gbar(&bars[1], 256u);

    // ---------- Phase 3: out[p][b][c] = sigmoid(W2[p][c][:] . h[p][b][:]) ----------
    {
        const int p   = bid >> 4;
        const int c0  = (bid & 15) * 128 + wib * 16;  // 16 c-rows per wave
        const int row = lane >> 2, q = lane & 3;

        const float4* hv = reinterpret_cast<const float4*>(h2);
        sm4[tid] = hv[p * 512 + tid];                 // stage h2[p] (8 KiB)
        __syncthreads();

        const float4* wr = reinterpret_cast<const float4*>(w2)
                         + ((size_t)p * C_ + c0 + row) * (CR_ / 4);
        float4 wv[8];
        #pragma unroll
        for (int j = 0; j < 8; ++j) wv[j] = wr[q + 4 * j];

        float acc[16];
        #pragma unroll
        for (int b = 0; b < 16; ++b) acc[b] = 0.f;
        #pragma unroll
        for (int j = 0; j < 8; ++j) {
            const int k4 = q + 4 * j;                 // float4 index in k
            const int m  = k4 >> 1, kk = k4 & 1;      // h2 slice / half
            #pragma unroll
            for (int b = 0; b < 16; ++b) {
                float4 h4 = sm4[m * 32 + b * 2 + kk];
                acc[b] += wv[j].x * h4.x + wv[j].y * h4.y
                        + wv[j].z * h4.z + wv[j].w * h4.w;
            }
        }
        #pragma unroll
        for (int b = 0; b < 16; ++b) {
            acc[b] += __shfl_xor(acc[b], 1, 64);
            acc[b] += __shfl_xor(acc[b], 2, 64);
        }
        #pragma unroll
        for (int i = 0; i < 4; ++i) {
            float v = acc[i];
            v = (q == 1) ? acc[4 + i]  : v;
            v = (q == 2) ? acc[8 + i]  : v;
            v = (q == 3) ? acc[12 + i] : v;
            int b = q * 4 + i;
            out[(((size_t)p * B_ + b) << 11) + c0 + row] = 1.0f / (1.0f + expf(-v));
        }
    }
}

// ===================== Fallback: R4 3-kernel path =====================
__global__ void k_mean(const float* __restrict__ x, float* __restrict__ y) {
    int wave = blockIdx.x * (blockDim.x >> 6) + (threadIdx.x >> 6);
    int lane = threadIdx.x & 63;
    int row = lane >> 2, col = (lane & 3) * 4;
    const float* base = x + (size_t)wave * 4 * 4096 + (16 * 64 + 16) + row * 64 + col;
    float4 v0 = *reinterpret_cast<const float4*>(base);
    float4 v1 = *reinterpret_cast<const float4*>(base + 4096);
    float4 v2 = *reinterpret_cast<const float4*>(base + 8192);
    float4 v3 = *reinterpret_cast<const float4*>(base + 12288);
    float s0 = v0.x + v0.y + v0.z + v0.w;
    float s1 = v1.x + v1.y + v1.z + v1.w;
    float s2 = v2.x + v2.y + v2.z + v2.w;
    float s3 = v3.x + v3.y + v3.z + v3.w;
    #pragma unroll
    for (int m = 32; m >= 1; m >>= 1) {
        s0 += __shfl_xor(s0, m, 64); s1 += __shfl_xor(s1, m, 64);
        s2 += __shfl_xor(s2, m, 64); s3 += __shfl_xor(s3, m, 64);
    }
    float v = s0;
    v = (lane == 1) ? s1 : v; v = (lane == 2) ? s2 : v; v = (lane == 3) ? s3 : v;
    if (lane < 4) y[wave * 4 + lane] = v * (1.0f / 256.0f);
}

__global__ void __launch_bounds__(256) k_fc1(const float* __restrict__ w1,
                                             const float* __restrict__ y,
                                             float* __restrict__ h) {
    __shared__ float ys[B_ * C_];                 // 128 KiB
    int tid = threadIdx.x, wib = tid >> 6, lane = tid & 63;
    const float4* ysrc = reinterpret_cast<const float4*>(y);
    float4* ydst = reinterpret_cast<float4*>(ys);
    #pragma unroll 8
    for (int i = 0; i < 32; ++i) ydst[tid + 256 * i] = ysrc[tid + 256 * i];
    __syncthreads();
    int r0 = blockIdx.x * 8 + wib * 2;
    const float4* wr0 = reinterpret_cast<const float4*>(w1) + (size_t)r0 * 512;
    const float4* wr1 = wr0 + 512;
    float acc0[16], acc1[16];
    #pragma unroll
    for (int b = 0; b < 16; ++b) { acc0[b] = 0.f; acc1[b] = 0.f; }
    float4 pa = wr0[lane], pb = wr1[lane];
    #pragma unroll
    for (int i = 0; i < 8; ++i) {
        float4 wa = pa, wb = pb;
        if (i < 7) { pa = wr0[(i + 1) * 64 + lane]; pb = wr1[(i + 1) * 64 + lane]; }
        const float4* yrow = reinterpret_cast<const float4*>(ys) + i * 64 + lane;
        #pragma unroll
        for (int b = 0; b < 16; ++b) {
            float4 v = yrow[b * 512];
            acc0[b] += wa.x * v.x + wa.y * v.y + wa.z * v.z + wa.w * v.w;
            acc1[b] += wb.x * v.x + wb.y * v.y + wb.z * v.z + wb.w * v.w;
        }
    }
    #pragma unroll
    for (int b = 0; b < 16; ++b) {
        #pragma unroll
        for (int m = 32; m >= 1; m >>= 1) {
            acc0[b] += __shfl_xor(acc0[b], m, 64);
            acc1[b] += __shfl_xor(acc1[b], m, 64);
        }
    }
    float v0 = acc0[0], v1 = acc1[0];
    #pragma unroll
    for (int b = 1; b < 16; ++b) {
        v0 = (lane == b) ? acc0[b] : v0;
        v1 = (lane == b) ? acc1[b] : v1;
    }
    if (lane < 16) {
        int p = r0 >> 7, k = r0 & 127;
        h[(p * B_ + lane) * CR_ + k]     = fmaxf(v0, 0.f);
        h[(p * B_ + lane) * CR_ + k + 1] = fmaxf(v1, 0.f);
    }
}

__global__ void __launch_bounds__(256) k_fc2(const float* __restrict__ w2,
                                             const float* __restrict__ h,
                                             float* __restrict__ out) {
    __shared__ float hs[B_ * CR_];
    int wib = threadIdx.x >> 6;
    int wid = blockIdx.x * 4 + wib;
    int lane = threadIdx.x & 63;
    int p = wid >> 7, c0 = (wid & 127) << 4;
    int row = lane >> 2, q = lane & 3;
    const float4* hsrc = reinterpret_cast<const float4*>(h + (size_t)p * B_ * CR_);
    float4* hdst = reinterpret_cast<float4*>(hs);
    #pragma unroll
    for (int i = 0; i < 2; ++i) hdst[threadIdx.x + i * 256] = hsrc[threadIdx.x + i * 256];
    __syncthreads();
    const float4* wr = reinterpret_cast<const float4*>(w2)
                     + ((size_t)p * C_ + c0 + row) * (CR_ / 4);
    const float4* hv = reinterpret_cast<const float4*>(hs);
    float acc[16];
    #pragma unroll
    for (int b = 0; b < 16; ++b) acc[b] = 0.f;
    #pragma unroll
    for (int j = 0; j < 8; ++j) {
        float4 w4 = wr[q + 4 * j];
        #pragma unroll
        for (int b = 0; b < 16; ++b) {
            float4 h4 = hv[b * 32 + q + 4 * j];
            acc[b] += w4.x * h4.x + w4.y * h4.y + w4.z * h4.z + w4.w * h4.w;
        }
    }
    #pragma unroll
    for (int b = 0; b < 16; ++b) {
        acc[b] += __shfl_xor(acc[b], 1, 64);
        acc[b] += __shfl_xor(acc[b], 2, 64);
    }
    #pragma unroll
    for (int i = 0; i < 4; ++i) {
        float v = acc[i];
        v = (q == 1) ? acc[4 + i] : v;
        v = (q == 2) ? acc[8 + i] : v;
        v = (q == 3) ? acc[12 + i] : v;
        int b = q * 4 + i;
        out[(((size_t)p * B_ + b) << 11) + c0 + row] = 1.0f / (1.0f + expf(-v));
    }
}

extern "C" void kernel_launch(void* const* d_in, const int* in_sizes, int n_in,
                              void* d_out, int out_size, void* d_ws, size_t ws_size,
                              hipStream_t stream) {
    const float* x  = (const float*)d_in[0];
    const float* w1 = (const float*)d_in[1];
    const float* w2 = (const float*)d_in[2];
    float* out = (float*)d_out;
    float* y  = (float*)d_ws;                 // 32768 floats
    float* h2 = y + B_ * C_;                  // 32768 floats (padded layout)
    unsigned* bars = (unsigned*)((char*)d_ws + 2 * B_ * C_ * sizeof(float));

    // Zero the barrier counters every launch (graph-capturable, deterministic).
    hipMemsetAsync(bars, 0, 128, stream);

    void* args[] = { (void*)&x, (void*)&w1, (void*)&w2, (void*)&out,
                     (void*)&y, (void*)&h2, (void*)&bars };
    hipError_t err = hipLaunchCooperativeKernel((const void*)k_fused,
                                                dim3(256), dim3(512),
                                                args, 0, stream);
    if (err != hipSuccess) {
        // Fallback: 3-kernel path (deterministic; same result).
        k_mean<<<(B_ * C_ / 4) / 4, 256, 0, stream>>>(x, y);
        k_fc1<<<256, 256, 0, stream>>>(w1, y, (float*)h2);
        k_fc2<<<(P_ * C_ / 16) / 4, 256, 0, stream>>>(w2, (float*)h2, out);
    }
}

// Round 7
// 40.594 us; speedup vs baseline: 2.5503x; 2.1695x over previous
//
#include <hip/hip_runtime.h>
#include <math.h>

#define B_  16
#define C_  2048
#define P_  16
#define CR_ 128

// Kernel 1: y[b][c] = mean of x[b,c,16:32,16:32].
// One wave per 8 consecutive (b,c) patches; all 8 patch loads issued before
// any reduction -> 8 outstanding VMEM/wave, 16 waves/CU -> ~128 in flight/CU.
__global__ void __launch_bounds__(256) k_mean(const float* __restrict__ x,
                                              float* __restrict__ y) {
    int wave = blockIdx.x * (blockDim.x >> 6) + (threadIdx.x >> 6); // [0, 4096)
    int lane = threadIdx.x & 63;
    int row = lane >> 2, col = (lane & 3) * 4;
    const float* base = x + (size_t)wave * 8 * 4096 + (16 * 64 + 16)
                      + row * 64 + col;
    float4 v[8];
    #pragma unroll
    for (int j = 0; j < 8; ++j)
        v[j] = *reinterpret_cast<const float4*>(base + j * 4096);

    float s[8];
    #pragma unroll
    for (int j = 0; j < 8; ++j) s[j] = (v[j].x + v[j].y) + (v[j].z + v[j].w);

    #pragma unroll
    for (int m = 32; m >= 1; m >>= 1) {
        #pragma unroll
        for (int j = 0; j < 8; ++j) s[j] += __shfl_xor(s[j], m, 64);
    }

    float r = s[0];                    // static select (rule #20)
    r = (lane == 1) ? s[1] : r;
    r = (lane == 2) ? s[2] : r;
    r = (lane == 3) ? s[3] : r;
    r = (lane == 4) ? s[4] : r;
    r = (lane == 5) ? s[5] : r;
    r = (lane == 6) ? s[6] : r;
    r = (lane == 7) ? s[7] : r;
    if (lane < 8) y[wave * 8 + lane] = r * (1.0f / 256.0f);
}

// Kernel 2: h[p][b][k] = relu(sum_c W1[p][k][c] * y[b][c]).
// 256 blocks (1/CU), all of y staged in LDS (128 KiB), 2 rows/wave with the
// FULL W1 rows preloaded (16 independent dwordx4 in flight at 1 wave/SIMD).
__global__ void __launch_bounds__(256, 1) k_fc1(const float* __restrict__ w1,
                                                const float* __restrict__ y,
                                                float* __restrict__ h) {
    __shared__ float ys[B_ * C_];                 // 128 KiB
    int tid = threadIdx.x, wib = tid >> 6, lane = tid & 63;

    int r0 = blockIdx.x * 8 + wib * 2;            // rows r0, r0+1 (same p)
    const float4* wr0 = reinterpret_cast<const float4*>(w1) + (size_t)r0 * 512;
    const float4* wr1 = wr0 + 512;

    // Issue the full W1 row loads first (16 outstanding).
    float4 wA[8], wB[8];
    #pragma unroll
    for (int i = 0; i < 8; ++i) wA[i] = wr0[i * 64 + lane];
    #pragma unroll
    for (int i = 0; i < 8; ++i) wB[i] = wr1[i * 64 + lane];

    // Stage y while W1 is in flight.
    const float4* ysrc = reinterpret_cast<const float4*>(y);
    float4* ydst = reinterpret_cast<float4*>(ys);
    #pragma unroll 8
    for (int i = 0; i < 32; ++i) ydst[tid + 256 * i] = ysrc[tid + 256 * i];
    __syncthreads();

    float acc0[16], acc1[16];
    #pragma unroll
    for (int b = 0; b < 16; ++b) { acc0[b] = 0.f; acc1[b] = 0.f; }

    #pragma unroll
    for (int i = 0; i < 8; ++i) {
        const float4* yrow = reinterpret_cast<const float4*>(ys) + i * 64 + lane;
        #pragma unroll
        for (int b = 0; b < 16; ++b) {
            float4 v = yrow[b * 512];
            acc0[b] += wA[i].x * v.x + wA[i].y * v.y + wA[i].z * v.z + wA[i].w * v.w;
            acc1[b] += wB[i].x * v.x + wB[i].y * v.y + wB[i].z * v.z + wB[i].w * v.w;
        }
    }

    #pragma unroll
    for (int b = 0; b < 16; ++b) {
        #pragma unroll
        for (int m = 32; m >= 1; m >>= 1) {
            acc0[b] += __shfl_xor(acc0[b], m, 64);
            acc1[b] += __shfl_xor(acc1[b], m, 64);
        }
    }

    float v0 = acc0[0], v1 = acc1[0];
    #pragma unroll
    for (int b = 1; b < 16; ++b) {
        v0 = (lane == b) ? acc0[b] : v0;
        v1 = (lane == b) ? acc1[b] : v1;
    }
    if (lane < 16) {
        int p = r0 >> 7, k = r0 & 127;
        h[(p * B_ + lane) * CR_ + k]     = fmaxf(v0, 0.f);
        h[(p * B_ + lane) * CR_ + k + 1] = fmaxf(v1, 0.f);
    }
}

// Kernel 3: out[p][b][c] = sigmoid(sum_k W2[p][c][k] * h[p][b][k]).
// Wave = (p, 16 consecutive c rows); W2 read coalesced exactly once; h[p] in LDS.
__global__ void __launch_bounds__(256) k_fc2(const float* __restrict__ w2,
                                             const float* __restrict__ h,
                                             float* __restrict__ out) {
    __shared__ float hs[B_ * CR_];                // 8 KiB
    int wib = threadIdx.x >> 6;
    int wid = blockIdx.x * 4 + wib;               // [0, 2048)
    int lane = threadIdx.x & 63;
    int p = wid >> 7, c0 = (wid & 127) << 4;
    int row = lane >> 2, q = lane & 3;

    const float4* hsrc = reinterpret_cast<const float4*>(h + (size_t)p * B_ * CR_);
    float4* hdst = reinterpret_cast<float4*>(hs);
    #pragma unroll
    for (int i = 0; i < 2; ++i)
        hdst[threadIdx.x + i * 256] = hsrc[threadIdx.x + i * 256];
    __syncthreads();

    const float4* wr = reinterpret_cast<const float4*>(w2)
                     + ((size_t)p * C_ + c0 + row) * (CR_ / 4);
    float4 wv[8];
    #pragma unroll
    for (int j = 0; j < 8; ++j) wv[j] = wr[q + 4 * j];

    const float4* hv = reinterpret_cast<const float4*>(hs);
    float acc[16];
    #pragma unroll
    for (int b = 0; b < 16; ++b) acc[b] = 0.f;
    #pragma unroll
    for (int j = 0; j < 8; ++j) {
        #pragma unroll
        for (int b = 0; b < 16; ++b) {
            float4 h4 = hv[b * 32 + q + 4 * j];
            acc[b] += wv[j].x * h4.x + wv[j].y * h4.y
                    + wv[j].z * h4.z + wv[j].w * h4.w;
        }
    }
    #pragma unroll
    for (int b = 0; b < 16; ++b) {
        acc[b] += __shfl_xor(acc[b], 1, 64);
        acc[b] += __shfl_xor(acc[b], 2, 64);
    }
    #pragma unroll
    for (int i = 0; i < 4; ++i) {
        float v = acc[i];
        v = (q == 1) ? acc[4 + i]  : v;
        v = (q == 2) ? acc[8 + i]  : v;
        v = (q == 3) ? acc[12 + i] : v;
        int b = q * 4 + i;
        out[(((size_t)p * B_ + b) << 11) + c0 + row] = 1.0f / (1.0f + expf(-v));
    }
}

extern "C" void kernel_launch(void* const* d_in, const int* in_sizes, int n_in,
                              void* d_out, int out_size, void* d_ws, size_t ws_size,
                              hipStream_t stream) {
    const float* x  = (const float*)d_in[0];
    const float* w1 = (const float*)d_in[1];
    const float* w2 = (const float*)d_in[2];
    float* out = (float*)d_out;
    float* y = (float*)d_ws;                 // 32768 floats
    float* h = y + B_ * C_;                  // 32768 floats

    // 1) patch mean: 4096 waves x 8 patches
    k_mean<<<(B_ * C_ / 8) / 4, 256, 0, stream>>>(x, y);
    // 2) FC1 + relu: 256 blocks, y staged in LDS, 8 rows/block
    k_fc1<<<256, 256, 0, stream>>>(w1, y, h);
    // 3) FC2 + sigmoid: 512 blocks, one wave per 16 c-rows
    k_fc2<<<(P_ * C_ / 16) / 4, 256, 0, stream>>>(w2, h, out);
}